// Round 10
// baseline (193.032 us; speedup 1.0000x reference)
//
#include <hip/hip_runtime.h>
#include <math.h>

#define TILE 32
#define VB   36            // blurred region (rel coords -2..33)
#define MG   34            // magnitude region (rel coords -1..32)
#define NT   256

// Effective orientation-bin boundaries: ref computes rint((atan2*C+180)/45),
// C = 180/3.14159 (f64). Boundaries at angle (22.5+45j)/C rad, j=0..3 (folded
// by |gy| symmetry). cos/sin computed on HOST in f64, passed by value.
struct TrigC { double c0, s0, c1, s1, c2, s2, c3, s3; };

// f64 decision chain throughout: the np reference is f64 — full-f32 flipped an
// NMS decision (round-2); f64 passes with absmax=180 (hedge pixels only).
// Round-9 diagnosis: latency-bound (VALUBusy 40%, ~14us of f64 issue vs 90us
// measured), NOT f64-throughput-bound. This round: drop the raw LDS stage —
// blur h-taps read global directly (coalesced, L1/L2-resident window), LDS
// falls to vb+mag = 19616 B -> 8 blocks/CU, one dependent LDS hop and one
// barrier fewer. __launch_bounds__(256,8) caps VGPR at 64 (natural ~52).
__global__ __launch_bounds__(NT, 8) void canny_fused_kernel(
    const float* __restrict__ img,     // [B,3,H,W]
    const float* __restrict__ gauss,   // 5 floats
    float* __restrict__ out_blur,
    float* __restrict__ out_mag,
    float* __restrict__ out_ori,
    float* __restrict__ out_thin,
    float* __restrict__ out_thr,
    float* __restrict__ out_early,
    TrigC tc, int H, int W)
{
    __shared__ double s_vb [VB * VB];    // 10368 B
    __shared__ double s_mag[MG * MG];    // 9248 B

    const int tid = threadIdx.x;
    const int b   = blockIdx.z;
    const int gy0 = blockIdx.y * TILE;
    const int gx0 = blockIdx.x * TILE;
    // interior: blur window y in [gy0-4,gy0+36), x in [gx0-4,gx0+36) all in-image
    const bool interior = (gy0 >= 4) && (gy0 + 36 <= H) && (gx0 >= 4) && (gx0 + 36 <= W);

    const double g0 = (double)gauss[0], g1 = (double)gauss[1], g2 = (double)gauss[2];
    const size_t cs = (size_t)H * W;

    for (int i = tid; i < MG * MG; i += NT) s_mag[i] = 0.0;

    // per-thread gx/gy accumulators for 4 owned core pixels (i = tid + 256p)
    double agx0 = 0.0, agx1 = 0.0, agx2 = 0.0, agx3 = 0.0;
    double agy0 = 0.0, agy1 = 0.0, agy2 = 0.0, agy3 = 0.0;

    for (int c = 0; c < 3; ++c) {
        // ---- separable blur, rolling register h-window, h-taps from global:
        //      216 threads own one vb column xi for 6 rows.
        //      vb(yi,xi): rel (yi-2, xi-2); taps x = gx0+xi-4 .. gx0+xi,
        //      rows y = gy0+yi-4 .. gy0+yi. ----
        if (tid < 216) {
            const int xi = tid % 36;
            const int y0 = (tid / 36) * 6;          // yi = y0 .. y0+5
            const float* ip = img + (size_t)(b * 3 + c) * cs;
            const int xb = gx0 + xi - 4;
            const int gy = gy0 + y0 - 4;
            if (interior) {
                const float* colp = ip + xb;
                auto hrow = [&](int yy) -> double {
                    const float* p = colp + (size_t)yy * W;
                    return g0 * ((double)p[0] + (double)p[4])
                         + g1 * ((double)p[1] + (double)p[3])
                         + g2 * (double)p[2];
                };
                double h0 = hrow(gy),     h1 = hrow(gy + 1), h2 = hrow(gy + 2),
                       h3 = hrow(gy + 3), h4 = hrow(gy + 4);
#pragma unroll
                for (int t = 0; t < 6; ++t) {
                    s_vb[(y0 + t) * VB + xi] = g0 * (h0 + h4) + g1 * (h1 + h3) + g2 * h2;
                    if (t < 5) { h0 = h1; h1 = h2; h2 = h3; h3 = h4; h4 = hrow(gy + 5 + t); }
                }
            } else {
                auto hrow = [&](int yy) -> double {
                    if ((unsigned)yy >= (unsigned)H) return 0.0;
                    const float* p = ip + (size_t)yy * W;
                    double s = 0.0;
                    int x;
                    x = xb;     if ((unsigned)x < (unsigned)W) s += g0 * (double)p[x];
                    x = xb + 1; if ((unsigned)x < (unsigned)W) s += g1 * (double)p[x];
                    x = xb + 2; if ((unsigned)x < (unsigned)W) s += g2 * (double)p[x];
                    x = xb + 3; if ((unsigned)x < (unsigned)W) s += g1 * (double)p[x];
                    x = xb + 4; if ((unsigned)x < (unsigned)W) s += g0 * (double)p[x];
                    return s;
                };
                double h0 = hrow(gy),     h1 = hrow(gy + 1), h2 = hrow(gy + 2),
                       h3 = hrow(gy + 3), h4 = hrow(gy + 4);
#pragma unroll
                for (int t = 0; t < 6; ++t) {
                    int yi = y0 + t;
                    double acc = g0 * (h0 + h4) + g1 * (h1 + h3) + g2 * h2;
                    int y = gy0 + yi - 2, x = gx0 + xi - 2;
                    if ((unsigned)y >= (unsigned)H || (unsigned)x >= (unsigned)W) acc = 0.0;
                    s_vb[yi * VB + xi] = acc;
                    if (t < 5) { h0 = h1; h1 = h2; h2 = h3; h3 = h4; h4 = hrow(gy + 5 + t); }
                }
            }
        }
        __syncthreads();

        // ---- sobel -> mag, core pixels (reuse gx/gy for orientation accums;
        //      core px always in-image; unique writer per mag cell). ----
        {
            int ry = tid >> 5, rx = tid & 31;
#pragma unroll 4
            for (int p = 0; p < 4; ++p) {
                int my = ry + 8 * p + 1, mx = rx + 1;
                const double* v = s_vb + my * VB + mx;
                double a00 = v[0],      a01 = v[1],          a02 = v[2];
                double a10 = v[VB],                          a12 = v[VB + 2];
                double a20 = v[2 * VB], a21 = v[2 * VB + 1], a22 = v[2 * VB + 2];
                double gx = (a00 - a02) + 2.0 * (a10 - a12) + (a20 - a22);
                double gy = (a00 - a20) + 2.0 * (a01 - a21) + (a02 - a22);
                s_mag[my * MG + mx] += sqrt(gx * gx + gy * gy);
                if (p == 0) { agx0 += gx; agy0 += gy; }
                else if (p == 1) { agx1 += gx; agy1 += gy; }
                else if (p == 2) { agx2 += gx; agy2 += gy; }
                else { agx3 += gx; agy3 += gy; }
            }
        }
        // ---- ring of mag (34x34 border, 132 px), zeroed outside image ----
        if (tid < 132) {
            int my, mx;
            if (tid < 34)       { my = 0;             mx = tid; }
            else if (tid < 68)  { my = 33;            mx = tid - 34; }
            else if (tid < 100) { my = tid - 68 + 1;  mx = 0; }
            else                { my = tid - 100 + 1; mx = 33; }
            bool inimg = interior;
            if (!interior) {
                int y = gy0 + my - 1, x = gx0 + mx - 1;
                inimg = ((unsigned)y < (unsigned)H) && ((unsigned)x < (unsigned)W);
            }
            if (inimg) {
                const double* v = s_vb + my * VB + mx;
                double a00 = v[0],      a01 = v[1],          a02 = v[2];
                double a10 = v[VB],                          a12 = v[VB + 2];
                double a20 = v[2 * VB], a21 = v[2 * VB + 1], a22 = v[2 * VB + 2];
                double gx = (a00 - a02) + 2.0 * (a10 - a12) + (a20 - a22);
                double gy = (a00 - a20) + 2.0 * (a01 - a21) + (a02 - a22);
                s_mag[my * MG + mx] += sqrt(gx * gx + gy * gy);
            }
        }
        {   // blurred core write (32x32), 4 px/thread
            float* bp = out_blur + (size_t)(b * 3 + c) * cs;
            int ry = tid >> 5, rx = tid & 31;
#pragma unroll 4
            for (int p = 0; p < 4; ++p)
                bp[(size_t)(gy0 + ry + 8 * p) * W + (gx0 + rx)] =
                    (float)s_vb[(ry + 8 * p + 2) * VB + (rx + 2)];
        }
        __syncthreads();   // vb fully consumed; next channel may overwrite
    }

    // ---- orientation bin (no atan2) + directional NMS + thresholds ----
    const size_t ob = (size_t)b * cs;
#pragma unroll 4
    for (int p = 0; p < 4; ++p) {
        int i = tid + p * NT;
        int ry = i >> 5, rx = i & 31;
        double gxv = (p == 0) ? agx0 : (p == 1) ? agx1 : (p == 2) ? agx2 : agx3;
        double gyv = (p == 0) ? agy0 : (p == 1) ? agy1 : (p == 2) ? agy2 : agy3;
        double m = s_mag[(ry + 1) * MG + (rx + 1)];

        // k = rint((atan2(gy,gx)*C+180)/45) via half-plane tests. Fold by |gy|:
        // n = #boundaries below angle(gx,|gy|); k = 4 +/- n by sign(gy).
        double a = fabs(gyv);
        int n = (int)(a * tc.c0 - gxv * tc.s0 >= 0.0)
              + (int)(a * tc.c1 - gxv * tc.s1 >= 0.0)
              + (int)(a * tc.c2 - gxv * tc.s2 >= 0.0)
              + (int)(a * tc.c3 - gxv * tc.s3 >= 0.0);
        int k;
        if (gyv == 0.0) {   // replicate IEEE atan2 signed-zero conventions
            bool gxneg = signbit(gxv);
            k = signbit(gyv) ? (gxneg ? 0 : 4) : (gxneg ? 8 : 4);
        } else {
            k = signbit(gyv) ? 4 - n : 4 + n;
        }
        float q = 45.f * (float)k;
        // Branch-cut hedge: gy~0, gx<0 -> ref's last-ulp noise picks 0 or 360;
        // emit 180 (within 180 of both). NMS unaffected: k=0,k=8 alias mod 8.
        if (gxv < 0.0 && fabs(gyv) < 1e-2) q = 180.f;

        int kp = k & 7;
        // dy: k=0..7 -> 0,1,1,1,0,-1,-1,-1 ; dx: 1,1,0,-1,-1,-1,0,1 (nibble +1)
        int dy = (int)((0x00012221u >> (kp * 4)) & 7u) - 1;
        int dx = (int)((0x21000122u >> (kp * 4)) & 7u) - 1;
        double pos = m - s_mag[(ry + 1 + dy) * MG + (rx + 1 + dx)];
        double neg = m - s_mag[(ry + 1 - dy) * MG + (rx + 1 - dx)];
        float mf = (float)m;
        float thin = (fmin(pos, neg) > 0.0) ? mf : 0.f;
        size_t idx = ob + (size_t)(gy0 + ry) * W + (gx0 + rx);
        out_mag[idx]   = mf;
        out_ori[idx]   = q;
        out_thin[idx]  = thin;
        out_thr[idx]   = (thin < 10.f) ? 0.f : thin;
        out_early[idx] = (mf < 10.f) ? 0.f : mf;
    }
}

extern "C" void kernel_launch(void* const* d_in, const int* in_sizes, int n_in,
                              void* d_out, int out_size, void* d_ws, size_t ws_size,
                              hipStream_t stream) {
    const float* img   = (const float*)d_in[0];
    const float* gauss = (const float*)d_in[1];
    const int H = 1024, W = 1024;
    const int B = in_sizes[0] / (3 * H * W);

    float* out = (float*)d_out;
    const size_t cs = (size_t)H * W;
    float* out_blur  = out;
    float* out_mag   = out_blur + (size_t)B * 3 * cs;
    float* out_ori   = out_mag  + (size_t)B * cs;
    float* out_thin  = out_ori  + (size_t)B * cs;
    float* out_thr   = out_thin + (size_t)B * cs;
    float* out_early = out_thr  + (size_t)B * cs;

    // Host-side f64 boundary trig (graph-capture safe: pure computation).
    const double C = 180.0 / 3.14159;
    TrigC tc;
    { double bta = 22.5 / C;  tc.c0 = cos(bta); tc.s0 = sin(bta); }
    { double bta = 67.5 / C;  tc.c1 = cos(bta); tc.s1 = sin(bta); }
    { double bta = 112.5 / C; tc.c2 = cos(bta); tc.s2 = sin(bta); }
    { double bta = 157.5 / C; tc.c3 = cos(bta); tc.s3 = sin(bta); }

    dim3 grid(W / TILE, H / TILE, B);
    canny_fused_kernel<<<grid, NT, 0, stream>>>(
        img, gauss, out_blur, out_mag, out_ori, out_thin, out_thr, out_early, tc, H, W);
}

// Round 11
// 154.400 us; speedup vs baseline: 1.2502x; 1.2502x over previous
//
#include <hip/hip_runtime.h>
#include <math.h>

#define TILE 32
#define VB   36            // blurred region (rel coords -2..33)
#define MG   34            // magnitude region (rel coords -1..32)
#define NT   256

// Effective orientation-bin boundaries: ref computes rint((atan2*C+180)/45),
// C = 180/3.14159 (f64). Boundaries at angle (22.5+45j)/C rad, j=0..3 (folded
// by |gy| symmetry). cos/sin computed on HOST in f64, passed by value.
struct TrigC { double c0, s0, c1, s1, c2, s2, c3, s3; };

// f64 decision chain throughout: the np reference is f64 — full-f32 flipped an
// NMS decision (round-2); f64 passes with absmax=180 (hedge pixels only).
// Structure (round-10): no raw LDS stage — blur h-taps read global directly
// (coalesced, L1-resident window); LDS = vb+mag = 19616 B.
// __launch_bounds__(256,4): (256,8) forced VGPR->32 and spilled (round-10:
// WRITE 303MB vs 131MB true outputs, 646MB total traffic = the whole 232us).
// (256,6) did the same in round-5. VGPR cap 128 >= natural ~60-84: no spill.
__global__ __launch_bounds__(NT, 4) void canny_fused_kernel(
    const float* __restrict__ img,     // [B,3,H,W]
    const float* __restrict__ gauss,   // 5 floats
    float* __restrict__ out_blur,
    float* __restrict__ out_mag,
    float* __restrict__ out_ori,
    float* __restrict__ out_thin,
    float* __restrict__ out_thr,
    float* __restrict__ out_early,
    TrigC tc, int H, int W)
{
    __shared__ double s_vb [VB * VB];    // 10368 B
    __shared__ double s_mag[MG * MG];    // 9248 B

    const int tid = threadIdx.x;
    const int b   = blockIdx.z;
    const int gy0 = blockIdx.y * TILE;
    const int gx0 = blockIdx.x * TILE;
    // interior: blur window y in [gy0-4,gy0+36), x in [gx0-4,gx0+36) all in-image
    const bool interior = (gy0 >= 4) && (gy0 + 36 <= H) && (gx0 >= 4) && (gx0 + 36 <= W);

    const double g0 = (double)gauss[0], g1 = (double)gauss[1], g2 = (double)gauss[2];
    const size_t cs = (size_t)H * W;

    for (int i = tid; i < MG * MG; i += NT) s_mag[i] = 0.0;

    // per-thread gx/gy accumulators for 4 owned core pixels (i = tid + 256p)
    double agx0 = 0.0, agx1 = 0.0, agx2 = 0.0, agx3 = 0.0;
    double agy0 = 0.0, agy1 = 0.0, agy2 = 0.0, agy3 = 0.0;

    for (int c = 0; c < 3; ++c) {
        // ---- separable blur, rolling register h-window, h-taps from global:
        //      216 threads own one vb column xi for 6 rows.
        //      vb(yi,xi): rel (yi-2, xi-2); taps x = gx0+xi-4 .. gx0+xi,
        //      rows y = gy0+yi-4 .. gy0+yi. ----
        if (tid < 216) {
            const int xi = tid % 36;
            const int y0 = (tid / 36) * 6;          // yi = y0 .. y0+5
            const float* ip = img + (size_t)(b * 3 + c) * cs;
            const int xb = gx0 + xi - 4;
            const int gy = gy0 + y0 - 4;
            if (interior) {
                const float* colp = ip + xb;
                auto hrow = [&](int yy) -> double {
                    const float* p = colp + (size_t)yy * W;
                    return g0 * ((double)p[0] + (double)p[4])
                         + g1 * ((double)p[1] + (double)p[3])
                         + g2 * (double)p[2];
                };
                double h0 = hrow(gy),     h1 = hrow(gy + 1), h2 = hrow(gy + 2),
                       h3 = hrow(gy + 3), h4 = hrow(gy + 4);
#pragma unroll
                for (int t = 0; t < 6; ++t) {
                    s_vb[(y0 + t) * VB + xi] = g0 * (h0 + h4) + g1 * (h1 + h3) + g2 * h2;
                    if (t < 5) { h0 = h1; h1 = h2; h2 = h3; h3 = h4; h4 = hrow(gy + 5 + t); }
                }
            } else {
                auto hrow = [&](int yy) -> double {
                    if ((unsigned)yy >= (unsigned)H) return 0.0;
                    const float* p = ip + (size_t)yy * W;
                    double s = 0.0;
                    int x;
                    x = xb;     if ((unsigned)x < (unsigned)W) s += g0 * (double)p[x];
                    x = xb + 1; if ((unsigned)x < (unsigned)W) s += g1 * (double)p[x];
                    x = xb + 2; if ((unsigned)x < (unsigned)W) s += g2 * (double)p[x];
                    x = xb + 3; if ((unsigned)x < (unsigned)W) s += g1 * (double)p[x];
                    x = xb + 4; if ((unsigned)x < (unsigned)W) s += g0 * (double)p[x];
                    return s;
                };
                double h0 = hrow(gy),     h1 = hrow(gy + 1), h2 = hrow(gy + 2),
                       h3 = hrow(gy + 3), h4 = hrow(gy + 4);
#pragma unroll
                for (int t = 0; t < 6; ++t) {
                    int yi = y0 + t;
                    double acc = g0 * (h0 + h4) + g1 * (h1 + h3) + g2 * h2;
                    int y = gy0 + yi - 2, x = gx0 + xi - 2;
                    if ((unsigned)y >= (unsigned)H || (unsigned)x >= (unsigned)W) acc = 0.0;
                    s_vb[yi * VB + xi] = acc;
                    if (t < 5) { h0 = h1; h1 = h2; h2 = h3; h3 = h4; h4 = hrow(gy + 5 + t); }
                }
            }
        }
        __syncthreads();

        // ---- sobel -> mag, core pixels (reuse gx/gy for orientation accums;
        //      core px always in-image; unique writer per mag cell). ----
        {
            int ry = tid >> 5, rx = tid & 31;
#pragma unroll 4
            for (int p = 0; p < 4; ++p) {
                int my = ry + 8 * p + 1, mx = rx + 1;
                const double* v = s_vb + my * VB + mx;
                double a00 = v[0],      a01 = v[1],          a02 = v[2];
                double a10 = v[VB],                          a12 = v[VB + 2];
                double a20 = v[2 * VB], a21 = v[2 * VB + 1], a22 = v[2 * VB + 2];
                double gx = (a00 - a02) + 2.0 * (a10 - a12) + (a20 - a22);
                double gy = (a00 - a20) + 2.0 * (a01 - a21) + (a02 - a22);
                s_mag[my * MG + mx] += sqrt(gx * gx + gy * gy);
                if (p == 0) { agx0 += gx; agy0 += gy; }
                else if (p == 1) { agx1 += gx; agy1 += gy; }
                else if (p == 2) { agx2 += gx; agy2 += gy; }
                else { agx3 += gx; agy3 += gy; }
            }
        }
        // ---- ring of mag (34x34 border, 132 px), zeroed outside image ----
        if (tid < 132) {
            int my, mx;
            if (tid < 34)       { my = 0;             mx = tid; }
            else if (tid < 68)  { my = 33;            mx = tid - 34; }
            else if (tid < 100) { my = tid - 68 + 1;  mx = 0; }
            else                { my = tid - 100 + 1; mx = 33; }
            bool inimg = interior;
            if (!interior) {
                int y = gy0 + my - 1, x = gx0 + mx - 1;
                inimg = ((unsigned)y < (unsigned)H) && ((unsigned)x < (unsigned)W);
            }
            if (inimg) {
                const double* v = s_vb + my * VB + mx;
                double a00 = v[0],      a01 = v[1],          a02 = v[2];
                double a10 = v[VB],                          a12 = v[VB + 2];
                double a20 = v[2 * VB], a21 = v[2 * VB + 1], a22 = v[2 * VB + 2];
                double gx = (a00 - a02) + 2.0 * (a10 - a12) + (a20 - a22);
                double gy = (a00 - a20) + 2.0 * (a01 - a21) + (a02 - a22);
                s_mag[my * MG + mx] += sqrt(gx * gx + gy * gy);
            }
        }
        {   // blurred core write (32x32), 4 px/thread
            float* bp = out_blur + (size_t)(b * 3 + c) * cs;
            int ry = tid >> 5, rx = tid & 31;
#pragma unroll 4
            for (int p = 0; p < 4; ++p)
                bp[(size_t)(gy0 + ry + 8 * p) * W + (gx0 + rx)] =
                    (float)s_vb[(ry + 8 * p + 2) * VB + (rx + 2)];
        }
        __syncthreads();   // vb fully consumed; next channel may overwrite
    }

    // ---- orientation bin (no atan2) + directional NMS + thresholds ----
    const size_t ob = (size_t)b * cs;
#pragma unroll 4
    for (int p = 0; p < 4; ++p) {
        int i = tid + p * NT;
        int ry = i >> 5, rx = i & 31;
        double gxv = (p == 0) ? agx0 : (p == 1) ? agx1 : (p == 2) ? agx2 : agx3;
        double gyv = (p == 0) ? agy0 : (p == 1) ? agy1 : (p == 2) ? agy2 : agy3;
        double m = s_mag[(ry + 1) * MG + (rx + 1)];

        // k = rint((atan2(gy,gx)*C+180)/45) via half-plane tests. Fold by |gy|:
        // n = #boundaries below angle(gx,|gy|); k = 4 +/- n by sign(gy).
        double a = fabs(gyv);
        int n = (int)(a * tc.c0 - gxv * tc.s0 >= 0.0)
              + (int)(a * tc.c1 - gxv * tc.s1 >= 0.0)
              + (int)(a * tc.c2 - gxv * tc.s2 >= 0.0)
              + (int)(a * tc.c3 - gxv * tc.s3 >= 0.0);
        int k;
        if (gyv == 0.0) {   // replicate IEEE atan2 signed-zero conventions
            bool gxneg = signbit(gxv);
            k = signbit(gyv) ? (gxneg ? 0 : 4) : (gxneg ? 8 : 4);
        } else {
            k = signbit(gyv) ? 4 - n : 4 + n;
        }
        float q = 45.f * (float)k;
        // Branch-cut hedge: gy~0, gx<0 -> ref's last-ulp noise picks 0 or 360;
        // emit 180 (within 180 of both). NMS unaffected: k=0,k=8 alias mod 8.
        if (gxv < 0.0 && fabs(gyv) < 1e-2) q = 180.f;

        int kp = k & 7;
        // dy: k=0..7 -> 0,1,1,1,0,-1,-1,-1 ; dx: 1,1,0,-1,-1,-1,0,1 (nibble +1)
        int dy = (int)((0x00012221u >> (kp * 4)) & 7u) - 1;
        int dx = (int)((0x21000122u >> (kp * 4)) & 7u) - 1;
        double pos = m - s_mag[(ry + 1 + dy) * MG + (rx + 1 + dx)];
        double neg = m - s_mag[(ry + 1 - dy) * MG + (rx + 1 - dx)];
        float mf = (float)m;
        float thin = (fmin(pos, neg) > 0.0) ? mf : 0.f;
        size_t idx = ob + (size_t)(gy0 + ry) * W + (gx0 + rx);
        out_mag[idx]   = mf;
        out_ori[idx]   = q;
        out_thin[idx]  = thin;
        out_thr[idx]   = (thin < 10.f) ? 0.f : thin;
        out_early[idx] = (mf < 10.f) ? 0.f : mf;
    }
}

extern "C" void kernel_launch(void* const* d_in, const int* in_sizes, int n_in,
                              void* d_out, int out_size, void* d_ws, size_t ws_size,
                              hipStream_t stream) {
    const float* img   = (const float*)d_in[0];
    const float* gauss = (const float*)d_in[1];
    const int H = 1024, W = 1024;
    const int B = in_sizes[0] / (3 * H * W);

    float* out = (float*)d_out;
    const size_t cs = (size_t)H * W;
    float* out_blur  = out;
    float* out_mag   = out_blur + (size_t)B * 3 * cs;
    float* out_ori   = out_mag  + (size_t)B * cs;
    float* out_thin  = out_ori  + (size_t)B * cs;
    float* out_thr   = out_thin + (size_t)B * cs;
    float* out_early = out_thr  + (size_t)B * cs;

    // Host-side f64 boundary trig (graph-capture safe: pure computation).
    const double C = 180.0 / 3.14159;
    TrigC tc;
    { double bta = 22.5 / C;  tc.c0 = cos(bta); tc.s0 = sin(bta); }
    { double bta = 67.5 / C;  tc.c1 = cos(bta); tc.s1 = sin(bta); }
    { double bta = 112.5 / C; tc.c2 = cos(bta); tc.s2 = sin(bta); }
    { double bta = 157.5 / C; tc.c3 = cos(bta); tc.s3 = sin(bta); }

    dim3 grid(W / TILE, H / TILE, B);
    canny_fused_kernel<<<grid, NT, 0, stream>>>(
        img, gauss, out_blur, out_mag, out_ori, out_thin, out_thr, out_early, tc, H, W);
}

// Round 12
// 79.559 us; speedup vs baseline: 2.4263x; 1.9407x over previous
//
#include <hip/hip_runtime.h>
#include <math.h>

// Wave-autonomous column sweep: 1 wave = 64 lanes = 64 consecutive x.
// Lanes 0..63 load raw; h valid lanes 2..61; gx/gy/mag valid 3..60;
// outputs written by lanes 4..59 (56 columns per strip).
// No LDS, no barriers: vertical state in rolling registers, horizontal
// neighbors via __shfl. All decision expressions keep the round-9 passing
// kernel's exact association (f64; np reference is f64 — f32 flipped NMS).
// __launch_bounds__(64,2): VGPR cap 256 -> spill impossible (rounds 5/10:
// forced low caps spilled, FETCH+WRITE blew up 4x).

#define OUTW 56
#define ROWS 16
#define NT   64

struct TrigC { double c0,s0,c1,s1,c2,s2,c3,s3; };

struct ChS {
    double hA,hB,hC,hD;   // h rows v-2..v+1 (hE = row v+2 computed in-iter)
    double d0,d1;         // d rows v-2, v-1   (d = vb[x-1]-vb[x+1])
    double v0,v1;         // vb rows v-2, v-1
    float  rwP;           // prefetched raw row v+2
};

__global__ __launch_bounds__(NT, 2) void canny_wave_kernel(
    const float* __restrict__ img,     // [B,3,H,W]
    const float* __restrict__ gauss,   // 5 floats
    float* __restrict__ out_blur,
    float* __restrict__ out_mag,
    float* __restrict__ out_ori,
    float* __restrict__ out_thin,
    float* __restrict__ out_thr,
    float* __restrict__ out_early,
    TrigC tc, int H, int W)
{
    const int lane  = threadIdx.x;          // 0..63
    const int strip = blockIdx.x;           // ceil(W/OUTW) strips
    const int seg   = blockIdx.y;           // H/ROWS segments
    const int b     = blockIdx.z;

    const int  x   = strip * OUTW + lane - 4;
    const bool xin = (unsigned)x < (unsigned)W;
    const int  r0  = seg * ROWS;

    const double g0 = (double)gauss[0], g1 = (double)gauss[1], g2 = (double)gauss[2];
    const size_t cs = (size_t)H * W;
    const float* ip0 = img + (size_t)(b * 3 + 0) * cs;
    const float* ip1 = ip0 + cs;
    const float* ip2 = ip1 + cs;
    float* bp0 = out_blur + (size_t)(b * 3 + 0) * cs;
    float* bp1 = bp0 + cs;
    float* bp2 = bp1 + cs;

    const bool outok = xin && lane >= 4 && lane <= 59;

    auto rawload = [&](const float* ip, int y) -> float {
        return (xin && (unsigned)y < (unsigned)H) ? ip[(size_t)y * W + x] : 0.f;
    };
    auto hconv = [&](float rw) -> double {   // valid lanes 2..61
        float m2 = __shfl(rw, lane - 2);
        float m1 = __shfl(rw, lane - 1);
        float p1 = __shfl(rw, lane + 1);
        float p2 = __shfl(rw, lane + 2);
        return g0 * ((double)m2 + (double)p2) + g1 * ((double)m1 + (double)p1)
             + g2 * (double)rw;
    };
    auto hinit = [&](const float* ip, ChS& s) {
        s.hA = hconv(rawload(ip, r0 - 4));
        s.hB = hconv(rawload(ip, r0 - 3));
        s.hC = hconv(rawload(ip, r0 - 2));
        s.hD = hconv(rawload(ip, r0 - 1));
        s.d0 = 0.0; s.d1 = 0.0; s.v0 = 0.0; s.v1 = 0.0;
        s.rwP = rawload(ip, r0);            // raw row for first iter (v=r0-2 -> v+2=r0)
    };
    // One channel, one iteration at vb-row v: produce vb(v), blur-store,
    // then sobel at row m=v-1 -> add to msum/gx/gy sums. Rolls its windows.
    auto chstep = [&](const float* ip, float* bp, ChS& s, int v,
                      double& msum, double& gxs, double& gys) {
        float  rw = s.rwP;
        s.rwP = rawload(ip, v + 3);          // prefetch next iter's raw row
        double hE = hconv(rw);               // h row v+2
        double vbn = g0 * (s.hA + hE) + g1 * (s.hB + s.hD) + g2 * s.hC;  // vb row v
        if (!xin || (unsigned)v >= (unsigned)H) vbn = 0.0;  // conv SAME zero-pad
        if (v >= r0 && v < r0 + ROWS && outok)
            bp[(size_t)v * W + x] = (float)vbn;
        double vbL = __shfl(vbn, lane - 1), vbR = __shfl(vbn, lane + 1);
        double dn = vbL - vbR;               // d row v   (a?0 - a?2)
        double cc = s.v0 - vbn;              // c row m: vb[m-1]-vb[m+1], own column
        double cL = __shfl(cc, lane - 1), cR = __shfl(cc, lane + 1);
        // identical association to the passing kernel:
        // gx = (a00-a02) + 2.0*(a10-a12) + (a20-a22)
        double gx = s.d0 + 2.0 * s.d1 + dn;
        // gy = (a00-a20) + 2.0*(a01-a21) + (a02-a22)
        double gy = cL + 2.0 * cc + cR;
        msum += sqrt(gx * gx + gy * gy);
        gxs += gx; gys += gy;
        s.hA = s.hB; s.hB = s.hC; s.hC = s.hD; s.hD = hE;
        s.d0 = s.d1; s.d1 = dn;
        s.v0 = s.v1; s.v1 = vbn;
    };

    ChS c0s, c1s, c2s;
    hinit(ip0, c0s); hinit(ip1, c1s); hinit(ip2, c2s);

    // rolling mag rows (and their x-1 / x+1 copies), rolling gx/gy sums
    double mg0 = 0.0, mg1 = 0.0, mgL0 = 0.0, mgL1 = 0.0, mgR0 = 0.0, mgR1 = 0.0;
    double gxp = 0.0, gyp = 0.0;
    const size_t ob = (size_t)b * cs;

    for (int v = r0 - 2; v <= r0 + ROWS + 1; ++v) {
        double msum = 0.0, gxn = 0.0, gyn = 0.0;
        chstep(ip0, bp0, c0s, v, msum, gxn, gyn);
        chstep(ip1, bp1, c1s, v, msum, gxn, gyn);
        chstep(ip2, bp2, c2s, v, msum, gxn, gyn);
        const int m = v - 1;
        const bool mv = ((unsigned)m < (unsigned)H) && xin && lane >= 3 && lane <= 60;
        double magn = mv ? msum : 0.0;       // mag row v-1, zero-padded semantics
        double mgLn = __shfl(magn, lane - 1);
        double mgRn = __shfl(magn, lane + 1);

        if (v >= r0 + 2 && outok) {
            const int r = v - 2;             // output row; mag rows r-1,r,r+1 = mg*,*1,n
            double m_c = mg1;
            double gxv = gxp, gyv = gyp;

            // orientation bin (no atan2): k = rint((atan2*C+180)/45) via
            // half-plane tests, folded by |gy|; IEEE signed-zero cases explicit.
            double a = fabs(gyv);
            int n = (int)(a * tc.c0 - gxv * tc.s0 >= 0.0)
                  + (int)(a * tc.c1 - gxv * tc.s1 >= 0.0)
                  + (int)(a * tc.c2 - gxv * tc.s2 >= 0.0)
                  + (int)(a * tc.c3 - gxv * tc.s3 >= 0.0);
            int k;
            if (gyv == 0.0) {
                bool gxneg = signbit(gxv);
                k = signbit(gyv) ? (gxneg ? 0 : 4) : (gxneg ? 8 : 4);
            } else {
                k = signbit(gyv) ? 4 - n : 4 + n;
            }
            float q = 45.f * (float)k;
            // branch-cut hedge: ref's last-ulp noise picks 0 or 360; emit 180.
            if (gxv < 0.0 && fabs(gyv) < 1e-2) q = 180.f;

            int kp = k & 7;
            // dy: k=0..7 -> 0,1,1,1,0,-1,-1,-1 ; dx: 1,1,0,-1,-1,-1,0,1
            int dy = (int)((0x00012221u >> (kp * 4)) & 7u) - 1;
            int dx = (int)((0x21000122u >> (kp * 4)) & 7u) - 1;

            // mag[(r+dy)][x+dx] and mag[(r-dy)][x-dx] from rolled trios
            double rL = (dy < 0) ? mgL0 : (dy > 0 ? mgLn : mgL1);
            double rC = (dy < 0) ? mg0  : (dy > 0 ? magn : mg1);
            double rR = (dy < 0) ? mgR0 : (dy > 0 ? mgRn : mgR1);
            double posn = (dx < 0) ? rL : (dx > 0 ? rR : rC);
            double sL = (dy > 0) ? mgL0 : (dy < 0 ? mgLn : mgL1);
            double sC = (dy > 0) ? mg0  : (dy < 0 ? magn : mg1);
            double sR = (dy > 0) ? mgR0 : (dy < 0 ? mgRn : mgR1);
            double negn = (dx > 0) ? sL : (dx < 0 ? sR : sC);

            double pos = m_c - posn;
            double neg = m_c - negn;
            float mf = (float)m_c;
            float thin = (fmin(pos, neg) > 0.0) ? mf : 0.f;
            size_t idx = ob + (size_t)r * W + x;
            out_mag[idx]   = mf;
            out_ori[idx]   = q;
            out_thin[idx]  = thin;
            out_thr[idx]   = (thin < 10.f) ? 0.f : thin;
            out_early[idx] = (mf < 10.f) ? 0.f : mf;
        }

        mg0 = mg1; mg1 = magn;
        mgL0 = mgL1; mgL1 = mgLn;
        mgR0 = mgR1; mgR1 = mgRn;
        gxp = gxn; gyp = gyn;
    }
}

extern "C" void kernel_launch(void* const* d_in, const int* in_sizes, int n_in,
                              void* d_out, int out_size, void* d_ws, size_t ws_size,
                              hipStream_t stream) {
    const float* img   = (const float*)d_in[0];
    const float* gauss = (const float*)d_in[1];
    const int H = 1024, W = 1024;
    const int B = in_sizes[0] / (3 * H * W);

    float* out = (float*)d_out;
    const size_t cs = (size_t)H * W;
    float* out_blur  = out;
    float* out_mag   = out_blur + (size_t)B * 3 * cs;
    float* out_ori   = out_mag  + (size_t)B * cs;
    float* out_thin  = out_ori  + (size_t)B * cs;
    float* out_thr   = out_thin + (size_t)B * cs;
    float* out_early = out_thr  + (size_t)B * cs;

    // Host-side f64 boundary trig (graph-capture safe: pure computation).
    const double C = 180.0 / 3.14159;
    TrigC tc;
    { double bta = 22.5 / C;  tc.c0 = cos(bta); tc.s0 = sin(bta); }
    { double bta = 67.5 / C;  tc.c1 = cos(bta); tc.s1 = sin(bta); }
    { double bta = 112.5 / C; tc.c2 = cos(bta); tc.s2 = sin(bta); }
    { double bta = 157.5 / C; tc.c3 = cos(bta); tc.s3 = sin(bta); }

    dim3 grid((W + OUTW - 1) / OUTW, H / ROWS, B);
    canny_wave_kernel<<<grid, NT, 0, stream>>>(
        img, gauss, out_blur, out_mag, out_ori, out_thin, out_thr, out_early, tc, H, W);
}